// Round 1
// 259.229 us; speedup vs baseline: 1.0941x; 1.0941x over previous
//
#include <hip/hip_runtime.h>
#include <math.h>

#define SS 32768
#define FQL_LDS_BYTES 147456   // X 64KB + Wq dbuf 2x32KB + Q 16KB

typedef _Float16 half4v __attribute__((ext_vector_type(4)));
typedef _Float16 half8v __attribute__((ext_vector_type(8)));
typedef float float4v __attribute__((ext_vector_type(4)));

__device__ __forceinline__ void gload16(const void* g, void* l) {
    __builtin_amdgcn_global_load_lds(
        (const __attribute__((address_space(1))) unsigned int*)g,
        (__attribute__((address_space(3))) unsigned int*)l, 16, 0, 0);
}

// ---------------------------------------------------------------------------
// K0a: x[b][c][s] fp32 -> x_t[b][s][c] fp16 (LDS tile transpose)  [unchanged]
// ---------------------------------------------------------------------------
__global__ __launch_bounds__(256)
void cvt_x_kernel(const float* __restrict__ x, _Float16* __restrict__ x_t)
{
    __shared__ float ls[64][65];
    const int b = blockIdx.z, c0 = blockIdx.y * 64, s0 = blockIdx.x * 64;
    const int t = threadIdx.x;
    const int tr = t >> 4, tc = t & 15;
#pragma unroll
    for (int p = 0; p < 4; p++) {
        int c_l = p * 16 + tr;
        float4v v = *(const float4v*)(x + (size_t)(b * 256 + c0 + c_l) * SS + s0 + tc * 4);
        ls[c_l][tc * 4 + 0] = v.x;
        ls[c_l][tc * 4 + 1] = v.y;
        ls[c_l][tc * 4 + 2] = v.z;
        ls[c_l][tc * 4 + 3] = v.w;
    }
    __syncthreads();
#pragma unroll
    for (int p = 0; p < 4; p++) {
        int s_l = p * 16 + tr;
        half4v h;
        h.x = (_Float16)ls[tc * 4 + 0][s_l];
        h.y = (_Float16)ls[tc * 4 + 1][s_l];
        h.z = (_Float16)ls[tc * 4 + 2][s_l];
        h.w = (_Float16)ls[tc * 4 + 3][s_l];
        *(half4v*)(x_t + ((size_t)b * SS + s0 + s_l) * 256 + c0 + tc * 4) = h;
    }
}

// ---------------------------------------------------------------------------
// K0b: all three weight casts in one launch. [unchanged]
// ---------------------------------------------------------------------------
__global__ __launch_bounds__(256)
void cvt_w3_kernel(const float* __restrict__ s0, _Float16* __restrict__ d0,
                   const float* __restrict__ s1, _Float16* __restrict__ d1,
                   const float* __restrict__ s2, _Float16* __restrict__ d2)
{
    int bx = blockIdx.x;
    const float* s; _Float16* d; int base;
    if (bx < 128)      { s = s0; d = d0; base = bx; }
    else if (bx < 160) { s = s1; d = d1; base = bx - 128; }
    else               { s = s2; d = d2; base = bx - 160; }
    int i = (base * 256 + threadIdx.x) * 4;
    float4v v = *(const float4v*)(s + i);
    half4v h;
    h.x = (_Float16)v.x; h.y = (_Float16)v.y; h.z = (_Float16)v.z; h.w = (_Float16)v.w;
    *(half4v*)(d + i) = h;
}

// ---------------------------------------------------------------------------
// K1: kv-only conv (q path removed -- q is fused into fq_logits now).
// Same 128x128 MFMA tile structure as before; grid 2560 -> 512 blocks.
// Writes 16.8MB instead of 83.9MB.
// ---------------------------------------------------------------------------
__global__ __launch_bounds__(256)
void convkv_kernel(const _Float16* __restrict__ x_t,
                   const _Float16* __restrict__ wkv,
                   const float* __restrict__ kv_b,
                   _Float16* __restrict__ kv_t)
{
    __shared__ _Float16 smem[128 * 136];          // aliases staging + epilogue
    _Float16* const Ws = smem;                    // [128][64] staging
    _Float16* const Xs = smem + 128 * 64;         // [128][64] staging
    const int b = blockIdx.y;
    const int s0 = blockIdx.x * 128;
    const int t = threadIdx.x;
    const int w = t >> 6, l = t & 63;
    const int om = (w & 1) * 64, sn = (w >> 1) * 64;

    const int lr = l >> 3;
    const int gch = ((l & 7) - lr) & 7;
    const int m15 = l & 15;
    const int sl0 = ((((l >> 4) + (l & 7)) & 7)) * 8;
    const int sl1 = ((((l >> 4) + 4 + (l & 7)) & 7)) * 8;

    float4v acc[4][4];
#pragma unroll
    for (int i = 0; i < 4; i++)
#pragma unroll
        for (int j = 0; j < 4; j++) acc[i][j] = (float4v){0.f, 0.f, 0.f, 0.f};

    const _Float16* wg = wkv + (size_t)(32 * w + lr) * 256 + gch * 8;
    const _Float16* xg = x_t + ((size_t)b * SS + s0 + 32 * w + lr) * 256 + gch * 8;
    _Float16* wl = &Ws[(32 * w) * 64];
    _Float16* xl = &Xs[(32 * w) * 64];

    for (int c0 = 0; c0 < 256; c0 += 64) {
#pragma unroll
        for (int rb = 0; rb < 4; rb++) {
            gload16(wg + (size_t)rb * 8 * 256 + c0, wl + rb * 8 * 64);
            gload16(xg + (size_t)rb * 8 * 256 + c0, xl + rb * 8 * 64);
        }
        __syncthreads();
#pragma unroll
        for (int ks = 0; ks < 2; ks++) {
            const int sl = ks ? sl1 : sl0;
            half8v a[4], bb[4];
#pragma unroll
            for (int i = 0; i < 4; i++)
                a[i] = *(const half8v*)&Ws[(om + i * 16 + m15) * 64 + sl];
#pragma unroll
            for (int j = 0; j < 4; j++)
                bb[j] = *(const half8v*)&Xs[(sn + j * 16 + m15) * 64 + sl];
#pragma unroll
            for (int i = 0; i < 4; i++)
#pragma unroll
                for (int j = 0; j < 4; j++)
                    acc[i][j] = __builtin_amdgcn_mfma_f32_16x16x32_f16(a[i], bb[j], acc[i][j], 0, 0, 0);
        }
        __syncthreads();
    }
    // epilogue: stage T[128s][136] fp16 then coalesced 16B stores
    const int qd = l >> 4, m = l & 15;
#pragma unroll
    for (int i = 0; i < 4; i++) {
        float bv[4];
#pragma unroll
        for (int r = 0; r < 4; r++) bv[r] = kv_b[om + i * 16 + qd * 4 + r];
#pragma unroll
        for (int j = 0; j < 4; j++) {
            half4v h;
            h.x = (_Float16)(acc[i][j].x + bv[0]);
            h.y = (_Float16)(acc[i][j].y + bv[1]);
            h.z = (_Float16)(acc[i][j].z + bv[2]);
            h.w = (_Float16)(acc[i][j].w + bv[3]);
            int s_l = sn + j * 16 + m;
            *(half4v*)&smem[s_l * 136 + om + i * 16 + qd * 4] = h;
        }
    }
    __syncthreads();
    const int sr = t >> 4, kk = t & 15;
#pragma unroll
    for (int p = 0; p < 8; p++) {
        int s_l = p * 16 + sr;
        half8v h8 = *(const half8v*)&smem[s_l * 136 + kk * 8];
        *(half8v*)(kv_t + ((size_t)b * SS + s0 + s_l) * 128 + kk * 8) = h8;
    }
}

// ---------------------------------------------------------------------------
// K2: FUSED q-projection + logits. Eliminates q_t (67MB write + 67MB read).
// Block = (hw-chunk of 4 columns, b), 512 threads (8 waves), 144KB dyn LDS.
//   Xs [128 s'=(qd,hwl)][256 c]  staged once  (XOR-swizzled, source-side)
//   W  [64 kdf][256 c] x2        double-buffered per nh
//   Qs [128 s'][64 kdf]          q tile, fp16, bank-swizzled
// Per nh: q-GEMM 64x128xK256 (256 MFMA) -> bias+fp16 -> Qs ->
//         logits 32x32 x K=(4hw*64kdf) (32 MFMA, waves 0-3; K-frags preloaded
//         in regs once -- K is nh-invariant). Partials to Lpart[chunk].
// Numerics identical to old path (q rounded to fp16 before contraction).
// ---------------------------------------------------------------------------
__global__ __launch_bounds__(512)
void fq_logits_kernel(const _Float16* __restrict__ x_t,
                      const _Float16* __restrict__ wq,
                      const float* __restrict__ q_b,
                      const _Float16* __restrict__ kv_t,
                      float* __restrict__ Lpart)
{
    extern __shared__ _Float16 sm[];
    _Float16* const Xs = sm;              // 32768 elems
    _Float16* const W0 = sm + 32768;      // 16384 elems
    _Float16* const W1 = sm + 49152;      // 16384 elems
    _Float16* const Qs = sm + 65536;      // 8192 elems

    const int chunk = blockIdx.x, b = blockIdx.y;
    const int hw0 = chunk * 4;
    const int t = threadIdx.x;
    const int w = t >> 6, l = t & 63;
    const int lq = l >> 4;
    const int l15 = l & 15;
    const int rh = l >> 5, ch = l & 31;

    // ---- stage X (once): LDS[r][j] holds global chunk j^(r&7) of row r
#pragma unroll
    for (int i = 0; i < 8; i++) {
        int r = w * 16 + i * 2 + rh;           // s' row 0..127
        int qd = r >> 2, hwl = r & 3;
        int sc = ch ^ (r & 7);
        gload16(x_t + ((size_t)b * SS + qd * 1024 + hw0 + hwl) * 256 + sc * 8,
                Xs + (w * 16 + i * 2) * 256);
    }
    // ---- stage W[nh=0]
#pragma unroll
    for (int i = 0; i < 4; i++) {
        int r = w * 8 + i * 2 + rh;            // kdf row 0..63
        int sc = ch ^ (r & 7);
        gload16(wq + (size_t)r * 256 + sc * 8, W0 + (w * 8 + i * 2) * 256);
    }

    // ---- preload K fragments (waves 0-3): reused for all 8 nh
    half8v bk[8];
    if (w < 4) {
        const int nj = w & 1;
        const int kd = nj * 16 + l15;
        const _Float16* kbase = kv_t + ((size_t)b * SS + (size_t)kd * 1024 + hw0) * 128;
#pragma unroll
        for (int ks = 0; ks < 8; ks++) {
            int kk = ks * 32 + lq * 8;
            bk[ks] = *(const half8v*)(kbase + (size_t)(kk >> 6) * 128 + (kk & 63));
        }
    }
    __syncthreads();                           // X + W0 resident (vmcnt drained)

    const int wm = w >> 2, wn = w & 3;
    const int m0 = wm * 32, n0 = wn * 32;
    float* const lp_base = Lpart + (((size_t)chunk * 2 + b) * 8) * 1024;

    for (int nh = 0; nh < 8; nh++) {
        _Float16* const Wcur = (nh & 1) ? W1 : W0;
        // issue next-W stage early (completes under the q-GEMM below)
        if (nh < 7) {
            _Float16* const Wnxt = (nh & 1) ? W0 : W1;
#pragma unroll
            for (int i = 0; i < 4; i++) {
                int r = w * 8 + i * 2 + rh;
                int sc = ch ^ (r & 7);
                gload16(wq + ((size_t)((nh + 1) * 64 + r)) * 256 + sc * 8,
                        Wnxt + (w * 8 + i * 2) * 256);
            }
        }
        // ---- q-GEMM: D[kdf 64][s' 128], K=256 (per-wave 32x32 tile)
        float4v qacc[2][2];
#pragma unroll
        for (int i = 0; i < 2; i++)
#pragma unroll
            for (int j = 0; j < 2; j++) qacc[i][j] = (float4v){0.f, 0.f, 0.f, 0.f};
#pragma unroll
        for (int ks = 0; ks < 8; ks++) {
            int c8 = (ks * 32 + lq * 8) ^ ((l & 7) << 3);   // swizzled slot
            half8v a0 = *(const half8v*)&Wcur[(m0 + l15) * 256 + c8];
            half8v a1 = *(const half8v*)&Wcur[(m0 + 16 + l15) * 256 + c8];
            half8v x0 = *(const half8v*)&Xs[(n0 + l15) * 256 + c8];
            half8v x1 = *(const half8v*)&Xs[(n0 + 16 + l15) * 256 + c8];
            qacc[0][0] = __builtin_amdgcn_mfma_f32_16x16x32_f16(a0, x0, qacc[0][0], 0, 0, 0);
            qacc[0][1] = __builtin_amdgcn_mfma_f32_16x16x32_f16(a0, x1, qacc[0][1], 0, 0, 0);
            qacc[1][0] = __builtin_amdgcn_mfma_f32_16x16x32_f16(a1, x0, qacc[1][0], 0, 0, 0);
            qacc[1][1] = __builtin_amdgcn_mfma_f32_16x16x32_f16(a1, x1, qacc[1][1], 0, 0, 0);
        }
        __syncthreads();   // barrier A: previous logits readers done with Qs
        // ---- bias + fp16 + write Qs (swizzle key works for stride-1 AND stride-4 access)
#pragma unroll
        for (int i = 0; i < 2; i++) {
            int kbase = m0 + i * 16 + lq * 4;
            float4v bv = *(const float4v*)(q_b + nh * 64 + kbase);
#pragma unroll
            for (int j = 0; j < 2; j++) {
                int sp = n0 + j * 16 + l15;
                int key = ((sp ^ (sp >> 2)) & 7) << 3;
                half4v h;
                h.x = (_Float16)(qacc[i][j].x + bv.x);
                h.y = (_Float16)(qacc[i][j].y + bv.y);
                h.z = (_Float16)(qacc[i][j].z + bv.z);
                h.w = (_Float16)(qacc[i][j].w + bv.w);
                *(half4v*)&Qs[sp * 64 + (kbase ^ key)] = h;
            }
        }
        __syncthreads();   // barrier B: Qs ready; W[nh+1] resident (vmcnt drained)
        // ---- logits: D3[qd 32][kd 32], K = 4hw*64kdf = 256 (waves 0-3 only)
        if (w < 4) {
            const int mi = w >> 1, nj = w & 1;
            const int qd = mi * 16 + l15;
            float4v lacc = (float4v){0.f, 0.f, 0.f, 0.f};
#pragma unroll
            for (int ks = 0; ks < 8; ks++) {
                int kk = ks * 32 + lq * 8;
                int sp = qd * 4 + (kk >> 6);
                int key = ((sp ^ (sp >> 2)) & 7) << 3;
                half8v a = *(const half8v*)&Qs[sp * 64 + ((kk & 63) ^ key)];
                lacc = __builtin_amdgcn_mfma_f32_16x16x32_f16(a, bk[ks], lacc, 0, 0, 0);
            }
            float* dst = lp_base + (size_t)nh * 1024;
#pragma unroll
            for (int rr = 0; rr < 4; rr++)
                dst[(mi * 16 + lq * 4 + rr) * 32 + nj * 16 + l15] = lacc[rr];
        }
    }
}

// ---------------------------------------------------------------------------
// K3: reduce 256 chunk-partials + softmax (scale 0.125). Regridded 2 -> 64
// blocks (old version: 2 blocks on 256 CUs, latency-bound). Two-phase:
// per-thread partial over 8 chunks -> LDS -> 32-lane-group shuffle softmax.
// ---------------------------------------------------------------------------
__global__ __launch_bounds__(256)
void softmax_kernel(const float* __restrict__ Lpart, float* __restrict__ Lsm)
{
    __shared__ float red[32][8][32];          // [chunk-slice][row-local][j]
    const int t = threadIdx.x;
    const int rl = t & 7, cs = t >> 3;
    const int row = blockIdx.x * 8 + rl;      // 0..511 = (b, nh, qd)
    const int b = row >> 8, nh = (row >> 5) & 7, qd = row & 31;
    float4v p[8];
#pragma unroll
    for (int j4 = 0; j4 < 8; j4++) p[j4] = (float4v){0.f, 0.f, 0.f, 0.f};
    for (int cc = 0; cc < 8; cc++) {
        int chunk = cs + cc * 32;
        const float* src = Lpart + (((size_t)chunk * 2 + b) * 8 + nh) * 1024 + qd * 32;
#pragma unroll
        for (int j4 = 0; j4 < 8; j4++) p[j4] += *(const float4v*)(src + j4 * 4);
    }
#pragma unroll
    for (int j4 = 0; j4 < 8; j4++) *(float4v*)&red[cs][rl][j4 * 4] = p[j4];
    __syncthreads();
    const int r2 = t >> 5, j = t & 31;
    float s = 0.f;
#pragma unroll
    for (int c2 = 0; c2 < 32; c2++) s += red[c2][r2][j];
    float mx = s;
#pragma unroll
    for (int off = 16; off >= 1; off >>= 1) mx = fmaxf(mx, __shfl_xor(mx, off, 32));
    float e = expf((s - mx) * 0.125f);
    float sum = e;
#pragma unroll
    for (int off = 16; off >= 1; off >>= 1) sum += __shfl_xor(sum, off, 32);
    Lsm[(size_t)(blockIdx.x * 8 + r2) * 32 + j] = e / sum;
}

// ---------------------------------------------------------------------------
// K4: attn @ V  [unchanged this round; candidate for MFMA+proj fusion next]
// ---------------------------------------------------------------------------
__global__ __launch_bounds__(256)
void attn_v_kernel(const _Float16* __restrict__ kv_t,
                   const float* __restrict__ attn,
                   _Float16* __restrict__ o_t)
{
    __shared__ float as_[2048];
    const int wq = blockIdx.x, hl = blockIdx.y;
    const int b = blockIdx.z >> 2, rc = blockIdx.z & 3;
    const int t = threadIdx.x;
    {
        const float* src = attn + (size_t)b * 8192 + rc * 2048;
#pragma unroll
        for (int ll = 0; ll < 2; ll++) {
            int idx = (t + ll * 256) * 4;
            *(float4v*)(&as_[idx]) = *(const float4v*)(src + idx);
        }
    }
    __syncthreads();
    const int q4 = t & 127;
    const int half = t >> 7;
    const int tt = q4 >> 4;
    const int vd = (q4 * 4) & 63;
    const int hw = hl * 256 + wq * 8 + tt;
    float4v vreg[32];
#pragma unroll
    for (int j = 0; j < 32; j++) {
        half4v hv = *(const half4v*)(kv_t + ((size_t)((b * 32 + j) * 1024 + hw)) * 128 + 64 + vd);
        vreg[j] = (float4v){(float)hv.x, (float)hv.y, (float)hv.z, (float)hv.w};
    }
    _Float16* outb = o_t + (size_t)b * SS * 512;
#pragma unroll 2
    for (int rr = 0; rr < 32; rr++) {
        int row_l = half * 32 + rr;
        int row = rc * 64 + row_l;
        int hh = row >> 5, d = row & 31;
        const float* arow = &as_[row_l * 32];
        float ax = 0.f, ay = 0.f, az = 0.f, aw = 0.f;
#pragma unroll
        for (int j4 = 0; j4 < 8; j4++) {
            float4v a4 = *(const float4v*)(&arow[j4 * 4]);
            float4v v0 = vreg[j4 * 4 + 0];
            float4v v1 = vreg[j4 * 4 + 1];
            float4v v2 = vreg[j4 * 4 + 2];
            float4v v3 = vreg[j4 * 4 + 3];
            ax = fmaf(a4.x, v0.x, ax); ay = fmaf(a4.x, v0.y, ay);
            az = fmaf(a4.x, v0.z, az); aw = fmaf(a4.x, v0.w, aw);
            ax = fmaf(a4.y, v1.x, ax); ay = fmaf(a4.y, v1.y, ay);
            az = fmaf(a4.y, v1.z, az); aw = fmaf(a4.y, v1.w, aw);
            ax = fmaf(a4.z, v2.x, ax); ay = fmaf(a4.z, v2.y, ay);
            az = fmaf(a4.z, v2.z, az); aw = fmaf(a4.z, v2.w, aw);
            ax = fmaf(a4.w, v3.x, ax); ay = fmaf(a4.w, v3.y, ay);
            az = fmaf(a4.w, v3.z, az); aw = fmaf(a4.w, v3.w, aw);
        }
        int hp = hh * 4 + hl;
        size_t sp = (size_t)d * 1024 + hp * 32 + wq;
        half4v o4;
        o4.x = (_Float16)ax; o4.y = (_Float16)ay; o4.z = (_Float16)az; o4.w = (_Float16)aw;
        *(half4v*)(outb + sp * 512 + q4 * 4) = o4;
    }
}

// ---------------------------------------------------------------------------
// K5: proj GEMM via MFMA + bias + layer_scale  [unchanged]
// ---------------------------------------------------------------------------
__global__ __launch_bounds__(256)
void proj_mfma_kernel(const _Float16* __restrict__ o_t,
                      const _Float16* __restrict__ wp,
                      const float* __restrict__ pb,
                      const float* __restrict__ ls,
                      float* __restrict__ out)
{
    __shared__ _Float16 Ws[128 * 64];
    __shared__ _Float16 Xs[128 * 64];
    const int b = blockIdx.y;
    const int bx = blockIdx.x;
    const int grp = bx >> 4, rem = bx & 15;
    const int s_tile = grp * 8 + (rem & 7);
    const int o_tile = rem >> 3;
    const int s0 = s_tile * 128, o0 = o_tile * 128;
    const int t = threadIdx.x;
    const int w = t >> 6, l = t & 63;
    const int om = (w & 1) * 64, sn = (w >> 1) * 64;

    const int lr = l >> 3;
    const int gch = ((l & 7) - lr) & 7;
    const int m15 = l & 15;
    const int sl0 = ((((l >> 4) + (l & 7)) & 7)) * 8;
    const int sl1 = ((((l >> 4) + 4 + (l & 7)) & 7)) * 8;

    float4v acc[4][4];
#pragma unroll
    for (int i = 0; i < 4; i++)
#pragma unroll
        for (int j = 0; j < 4; j++) acc[i][j] = (float4v){0.f, 0.f, 0.f, 0.f};

    const _Float16* wg = wp + (size_t)(o0 + 32 * w + lr) * 512 + gch * 8;
    const _Float16* xg = o_t + ((size_t)b * SS + s0 + 32 * w + lr) * 512 + gch * 8;
    _Float16* wl = &Ws[(32 * w) * 64];
    _Float16* xl = &Xs[(32 * w) * 64];

    for (int c0 = 0; c0 < 512; c0 += 64) {
#pragma unroll
        for (int rb = 0; rb < 4; rb++) {
            gload16(wg + (size_t)rb * 8 * 512 + c0, wl + rb * 8 * 64);
            gload16(xg + (size_t)rb * 8 * 512 + c0, xl + rb * 8 * 64);
        }
        __syncthreads();
#pragma unroll
        for (int ks = 0; ks < 2; ks++) {
            const int sl = ks ? sl1 : sl0;
            half8v a[4], bb[4];
#pragma unroll
            for (int i = 0; i < 4; i++)
                a[i] = *(const half8v*)&Ws[(om + i * 16 + m15) * 64 + sl];
#pragma unroll
            for (int j = 0; j < 4; j++)
                bb[j] = *(const half8v*)&Xs[(sn + j * 16 + m15) * 64 + sl];
#pragma unroll
            for (int i = 0; i < 4; i++)
#pragma unroll
                for (int j = 0; j < 4; j++)
                    acc[i][j] = __builtin_amdgcn_mfma_f32_16x16x32_f16(a[i], bb[j], acc[i][j], 0, 0, 0);
        }
        __syncthreads();
    }
    const int qd = l >> 4, m = l & 15;
#pragma unroll
    for (int i = 0; i < 4; i++) {
        float pbv[4], lsv[4];
#pragma unroll
        for (int r = 0; r < 4; r++) {
            int o = o0 + om + i * 16 + qd * 4 + r;
            pbv[r] = pb[o];
            lsv[r] = ls[o];
        }
#pragma unroll
        for (int j = 0; j < 4; j++) {
            int s = s0 + sn + j * 16 + m;
#pragma unroll
            for (int r = 0; r < 4; r++) {
                int o = o0 + om + i * 16 + qd * 4 + r;
                out[((size_t)b * 256 + o) * SS + s] = (acc[i][j][r] + pbv[r]) * lsv[r];
            }
        }
    }
}

extern "C" void kernel_launch(void* const* d_in, const int* in_sizes, int n_in,
                              void* d_out, int out_size, void* d_ws, size_t ws_size,
                              hipStream_t stream)
{
    const float* x      = (const float*)d_in[0];
    const float* q_w    = (const float*)d_in[1];
    const float* q_b    = (const float*)d_in[2];
    const float* kv_w   = (const float*)d_in[3];
    const float* kv_b   = (const float*)d_in[4];
    const float* proj_w = (const float*)d_in[5];
    const float* proj_b = (const float*)d_in[6];
    const float* ls     = (const float*)d_in[7];
    float* out = (float*)d_out;

    char* ws = (char*)d_ws;
    _Float16* x_t  = (_Float16*)(ws);                        // 33,554,432 B
    _Float16* o_t  = (_Float16*)(ws + 33554432);             // 67,108,864 B
    float*    Lpart= (float*)   (ws + 33554432);             // 16,777,216 B, aliases o_t:
                                                             //   Lpart dead (softmax read) before attn_v writes o_t
    _Float16* kv_t = (_Float16*)(ws + 100663296);            // 16,777,216 B
    float*    Lsm  = (float*)   (ws + 117440512);            //     65,536 B
    _Float16* wq   = (_Float16*)(ws + 117506048);            //    262,144 B
    _Float16* wkv  = (_Float16*)(ws + 117768192);            //     65,536 B
    _Float16* wp   = (_Float16*)(ws + 117833728);            //    262,144 B

    static bool fql_attr_set = false;
    if (!fql_attr_set) {
        hipFuncSetAttribute(reinterpret_cast<const void*>(fq_logits_kernel),
                            hipFuncAttributeMaxDynamicSharedMemorySize, FQL_LDS_BYTES);
        fql_attr_set = true;
    }

    cvt_x_kernel<<<dim3(512, 4, 2), 256, 0, stream>>>(x, x_t);
    cvt_w3_kernel<<<dim3(288), 256, 0, stream>>>(q_w, wq, kv_w, wkv, proj_w, wp);

    convkv_kernel<<<dim3(256, 2), 256, 0, stream>>>(x_t, wkv, kv_b, kv_t);
    fq_logits_kernel<<<dim3(256, 2), 512, FQL_LDS_BYTES, stream>>>(x_t, wq, q_b, kv_t, Lpart);
    softmax_kernel<<<dim3(64), 256, 0, stream>>>(Lpart, Lsm);
    attn_v_kernel<<<dim3(32, 4, 8), 256, 0, stream>>>(kv_t, Lsm, o_t);
    proj_mfma_kernel<<<dim3(512, 2), 256, 0, stream>>>(o_t, wp, proj_b, ls, out);
}

// Round 2
// 242.117 us; speedup vs baseline: 1.1714x; 1.0707x over previous
//
#include <hip/hip_runtime.h>
#include <math.h>

#define SS 32768
#define FQL_LDS_BYTES 149504   // X 64KB + Qs 4x16KB + scratch 18KB

typedef _Float16 half4v __attribute__((ext_vector_type(4)));
typedef _Float16 half8v __attribute__((ext_vector_type(8)));
typedef float float4v __attribute__((ext_vector_type(4)));

__device__ __forceinline__ void gload16(const void* g, void* l) {
    __builtin_amdgcn_global_load_lds(
        (const __attribute__((address_space(1))) unsigned int*)g,
        (__attribute__((address_space(3))) unsigned int*)l, 16, 0, 0);
}

// ---------------------------------------------------------------------------
// K0a: x[b][c][s] fp32 -> x_t[b][s][c] fp16 (LDS tile transpose)  [unchanged]
// ---------------------------------------------------------------------------
__global__ __launch_bounds__(256)
void cvt_x_kernel(const float* __restrict__ x, _Float16* __restrict__ x_t)
{
    __shared__ float ls[64][65];
    const int b = blockIdx.z, c0 = blockIdx.y * 64, s0 = blockIdx.x * 64;
    const int t = threadIdx.x;
    const int tr = t >> 4, tc = t & 15;
#pragma unroll
    for (int p = 0; p < 4; p++) {
        int c_l = p * 16 + tr;
        float4v v = *(const float4v*)(x + (size_t)(b * 256 + c0 + c_l) * SS + s0 + tc * 4);
        ls[c_l][tc * 4 + 0] = v.x;
        ls[c_l][tc * 4 + 1] = v.y;
        ls[c_l][tc * 4 + 2] = v.z;
        ls[c_l][tc * 4 + 3] = v.w;
    }
    __syncthreads();
#pragma unroll
    for (int p = 0; p < 4; p++) {
        int s_l = p * 16 + tr;
        half4v h;
        h.x = (_Float16)ls[tc * 4 + 0][s_l];
        h.y = (_Float16)ls[tc * 4 + 1][s_l];
        h.z = (_Float16)ls[tc * 4 + 2][s_l];
        h.w = (_Float16)ls[tc * 4 + 3][s_l];
        *(half4v*)(x_t + ((size_t)b * SS + s0 + s_l) * 256 + c0 + tc * 4) = h;
    }
}

// ---------------------------------------------------------------------------
// K0b: weight casts. q_w additionally reshuffled into MFMA-FRAGMENT layout:
//   wq_f[((nh*8+ks)*4+i)*512 + (lq*16+l15)*8 + e] = q_w[(nh*64+i*16+l15)*256
//                                                      + ks*32 + lq*8 + e]
// so a wave's A-frag load in fq_logits is 64 lanes x consecutive 16B (1KB
// coalesced) from the 256KB L2-resident buffer. kv/proj paths unchanged.
// ---------------------------------------------------------------------------
__global__ __launch_bounds__(256)
void cvt_w3_kernel(const float* __restrict__ s0, _Float16* __restrict__ d0,
                   const float* __restrict__ s1, _Float16* __restrict__ d1,
                   const float* __restrict__ s2, _Float16* __restrict__ d2)
{
    int bx = blockIdx.x;
    if (bx < 128) {
        int idx = (bx * 256 + threadIdx.x) * 4;
        int e = idx & 7;                 // 0 or 4
        int lane = (idx >> 3) & 63;
        int l15 = lane & 15, lq = lane >> 4;
        int blk = idx >> 9;
        int i = blk & 3, ks = (blk >> 2) & 7, nh = blk >> 5;
        const float* src = s0 + (size_t)(nh * 64 + i * 16 + l15) * 256 + ks * 32 + lq * 8 + e;
        float4v v = *(const float4v*)src;
        half4v hh;
        hh.x = (_Float16)v.x; hh.y = (_Float16)v.y; hh.z = (_Float16)v.z; hh.w = (_Float16)v.w;
        *(half4v*)(d0 + idx) = hh;
    } else {
        const float* s; _Float16* d; int base;
        if (bx < 160) { s = s1; d = d1; base = bx - 128; }
        else          { s = s2; d = d2; base = bx - 160; }
        int i = (base * 256 + threadIdx.x) * 4;
        float4v v = *(const float4v*)(s + i);
        half4v hh;
        hh.x = (_Float16)v.x; hh.y = (_Float16)v.y; hh.z = (_Float16)v.z; hh.w = (_Float16)v.w;
        *(half4v*)(d + i) = hh;
    }
}

// ---------------------------------------------------------------------------
// K1: kv-only conv via MFMA  [unchanged]
// ---------------------------------------------------------------------------
__global__ __launch_bounds__(256)
void convkv_kernel(const _Float16* __restrict__ x_t,
                   const _Float16* __restrict__ wkv,
                   const float* __restrict__ kv_b,
                   _Float16* __restrict__ kv_t)
{
    __shared__ _Float16 smem[128 * 136];
    _Float16* const Ws = smem;
    _Float16* const Xs = smem + 128 * 64;
    const int b = blockIdx.y;
    const int s0 = blockIdx.x * 128;
    const int t = threadIdx.x;
    const int w = t >> 6, l = t & 63;
    const int om = (w & 1) * 64, sn = (w >> 1) * 64;

    const int lr = l >> 3;
    const int gch = ((l & 7) - lr) & 7;
    const int m15 = l & 15;
    const int sl0 = ((((l >> 4) + (l & 7)) & 7)) * 8;
    const int sl1 = ((((l >> 4) + 4 + (l & 7)) & 7)) * 8;

    float4v acc[4][4];
#pragma unroll
    for (int i = 0; i < 4; i++)
#pragma unroll
        for (int j = 0; j < 4; j++) acc[i][j] = (float4v){0.f, 0.f, 0.f, 0.f};

    const _Float16* wg = wkv + (size_t)(32 * w + lr) * 256 + gch * 8;
    const _Float16* xg = x_t + ((size_t)b * SS + s0 + 32 * w + lr) * 256 + gch * 8;
    _Float16* wl = &Ws[(32 * w) * 64];
    _Float16* xl = &Xs[(32 * w) * 64];

    for (int c0 = 0; c0 < 256; c0 += 64) {
#pragma unroll
        for (int rb = 0; rb < 4; rb++) {
            gload16(wg + (size_t)rb * 8 * 256 + c0, wl + rb * 8 * 64);
            gload16(xg + (size_t)rb * 8 * 256 + c0, xl + rb * 8 * 64);
        }
        __syncthreads();
#pragma unroll
        for (int ks = 0; ks < 2; ks++) {
            const int sl = ks ? sl1 : sl0;
            half8v a[4], bb[4];
#pragma unroll
            for (int i = 0; i < 4; i++)
                a[i] = *(const half8v*)&Ws[(om + i * 16 + m15) * 64 + sl];
#pragma unroll
            for (int j = 0; j < 4; j++)
                bb[j] = *(const half8v*)&Xs[(sn + j * 16 + m15) * 64 + sl];
#pragma unroll
            for (int i = 0; i < 4; i++)
#pragma unroll
                for (int j = 0; j < 4; j++)
                    acc[i][j] = __builtin_amdgcn_mfma_f32_16x16x32_f16(a[i], bb[j], acc[i][j], 0, 0, 0);
        }
        __syncthreads();
    }
    const int qd = l >> 4, m = l & 15;
#pragma unroll
    for (int i = 0; i < 4; i++) {
        float bv[4];
#pragma unroll
        for (int r = 0; r < 4; r++) bv[r] = kv_b[om + i * 16 + qd * 4 + r];
#pragma unroll
        for (int j = 0; j < 4; j++) {
            half4v h;
            h.x = (_Float16)(acc[i][j].x + bv[0]);
            h.y = (_Float16)(acc[i][j].y + bv[1]);
            h.z = (_Float16)(acc[i][j].z + bv[2]);
            h.w = (_Float16)(acc[i][j].w + bv[3]);
            int s_l = sn + j * 16 + m;
            *(half4v*)&smem[s_l * 136 + om + i * 16 + qd * 4] = h;
        }
    }
    __syncthreads();
    const int sr = t >> 4, kk = t & 15;
#pragma unroll
    for (int p = 0; p < 8; p++) {
        int s_l = p * 16 + sr;
        half8v h8 = *(const half8v*)&smem[s_l * 136 + kk * 8];
        *(half8v*)(kv_t + ((size_t)b * SS + s0 + s_l) * 128 + kk * 8) = h8;
    }
}

// ---------------------------------------------------------------------------
// K2 v2: fused q-proj + logits.
//  - W fragments direct from global (wq_f, L2-resident) -- no W in LDS.
//  - X staged once, bijective swizzle LDS[r][p]=global[(p-4r)&31]: fragment
//    reads hit all 32 chunk-slots exactly 2x -> conflict-free (was 8-way).
//  - 64x64 wave tiles, 4 nh in flight (2 waves/nh) -> half the LDS traffic.
//  - logits: all 8 waves (nh-pair x K-half), pair-reduce via LDS scratch.
// LDS: Xs 64KB + Qs 4x16KB + scr 18KB = 146KB, 1 block/CU, 8 waves.
// ---------------------------------------------------------------------------
__global__ __launch_bounds__(512)
void fq_logits_kernel(const _Float16* __restrict__ x_t,
                      const _Float16* __restrict__ wq_f,
                      const float* __restrict__ q_b,
                      const _Float16* __restrict__ kv_t,
                      float* __restrict__ Lpart)
{
    extern __shared__ _Float16 sm[];
    _Float16* const Xs = sm;                    // [128][256] halves, swizzled
    _Float16* const Qs = sm + 32768;            // 4 slabs x [128][64]
    float* const scr = (float*)(sm + 65536);    // 4 x [32][36] f32

    const int chunk = blockIdx.x, b = blockIdx.y;
    const int hw0 = chunk * 4;
    const int t = threadIdx.x;
    const int w = t >> 6, l = t & 63;
    const int l15 = l & 15, lq = l >> 4;
    const int h = w >> 1;          // nh-within-group / pair id
    const int ns = w & 1;          // q-GEMM n-slab; logits K-half
    const int n0 = ns * 64;

    // ---- stage X: LDS[r][p] holds global chunk (p - 4r) & 31 of row r
#pragma unroll
    for (int ii = 0; ii < 8; ii++) {
        int r = w * 16 + ii * 2 + (l >> 5);
        int p = l & 31;
        int sc = (p - 4 * r) & 31;
        int qd = r >> 2, hwl = r & 3;
        gload16(x_t + ((size_t)b * SS + qd * 1024 + hw0 + hwl) * 256 + sc * 8,
                Xs + (w * 16 + ii * 2) * 256);
    }

    // ---- preload logits K fragments for this wave's K-half: bk[j*4+ks']
    half8v bk[8];
#pragma unroll
    for (int j = 0; j < 2; j++)
#pragma unroll
        for (int ksp = 0; ksp < 4; ksp++) {
            int kk = (ns * 4 + ksp) * 32 + lq * 8;
            bk[j * 4 + ksp] = *(const half8v*)(kv_t +
                ((size_t)b * SS + (size_t)(j * 16 + l15) * 1024 + hw0 + (kk >> 6)) * 128 + (kk & 63));
        }
    __syncthreads();                            // X resident

    _Float16* const Qs_h = Qs + h * 8192;
    float* const scr_h = scr + h * (32 * 36);
    float* const lp_g = Lpart + (((size_t)chunk * 2 + b) * 8) * 1024;

    for (int g = 0; g < 2; g++) {
        const int nh = g * 4 + h;
        // ---- q-GEMM: 64(kdf) x 64(s'), K=256; A-frags from global wq_f
        const _Float16* wf = wq_f + ((size_t)nh * 32) * 512 + (size_t)l * 8;
        half8v aF[4], aN[4];
#pragma unroll
        for (int i = 0; i < 4; i++) aF[i] = *(const half8v*)(wf + (size_t)i * 512);
        float4v acc[4][4];
#pragma unroll
        for (int i = 0; i < 4; i++)
#pragma unroll
            for (int j = 0; j < 4; j++) acc[i][j] = (float4v){0.f, 0.f, 0.f, 0.f};
#pragma unroll
        for (int ks = 0; ks < 8; ks++) {
            if (ks < 7) {
#pragma unroll
                for (int i = 0; i < 4; i++)
                    aN[i] = *(const half8v*)(wf + (size_t)((ks + 1) * 4 + i) * 512);
            }
            const int p8 = (((ks * 4 + lq) + 4 * (l15 & 7)) & 31) * 8;
            half8v bF[4];
#pragma unroll
            for (int j = 0; j < 4; j++)
                bF[j] = *(const half8v*)&Xs[(n0 + j * 16 + l15) * 256 + p8];
#pragma unroll
            for (int i = 0; i < 4; i++)
#pragma unroll
                for (int j = 0; j < 4; j++)
                    acc[i][j] = __builtin_amdgcn_mfma_f32_16x16x32_f16(aF[i], bF[j], acc[i][j], 0, 0, 0);
#pragma unroll
            for (int i = 0; i < 4; i++) aF[i] = aN[i];
        }
        // ---- epilogue: bias + fp16 -> Qs slab h (key-swizzled columns)
#pragma unroll
        for (int i = 0; i < 4; i++) {
            int kb = i * 16 + lq * 4;
            float4v bv = *(const float4v*)(q_b + nh * 64 + kb);
#pragma unroll
            for (int j = 0; j < 4; j++) {
                int sp = n0 + j * 16 + l15;
                int key = ((sp ^ (sp >> 2)) & 7) << 3;
                half4v hv;
                hv.x = (_Float16)(acc[i][j].x + bv.x);
                hv.y = (_Float16)(acc[i][j].y + bv.y);
                hv.z = (_Float16)(acc[i][j].z + bv.z);
                hv.w = (_Float16)(acc[i][j].w + bv.w);
                *(half4v*)&Qs_h[sp * 64 + (kb ^ key)] = hv;
            }
        }
        __syncthreads();        // (1) all Qs slabs ready
        // ---- logits: full 32x32 per wave, K-half ns (ks' = 0..3)
        float4v lacc[2][2];
#pragma unroll
        for (int i = 0; i < 2; i++)
#pragma unroll
            for (int j = 0; j < 2; j++) lacc[i][j] = (float4v){0.f, 0.f, 0.f, 0.f};
#pragma unroll
        for (int ksp = 0; ksp < 4; ksp++) {
            int kk = (ns * 4 + ksp) * 32 + lq * 8;
            half8v a0, a1;
            {
                int sp = l15 * 4 + (kk >> 6);
                int key = ((sp ^ (sp >> 2)) & 7) << 3;
                a0 = *(const half8v*)&Qs_h[sp * 64 + ((kk & 63) ^ key)];
            }
            {
                int sp = (16 + l15) * 4 + (kk >> 6);
                int key = ((sp ^ (sp >> 2)) & 7) << 3;
                a1 = *(const half8v*)&Qs_h[sp * 64 + ((kk & 63) ^ key)];
            }
            lacc[0][0] = __builtin_amdgcn_mfma_f32_16x16x32_f16(a0, bk[ksp],     lacc[0][0], 0, 0, 0);
            lacc[0][1] = __builtin_amdgcn_mfma_f32_16x16x32_f16(a0, bk[4 + ksp], lacc[0][1], 0, 0, 0);
            lacc[1][0] = __builtin_amdgcn_mfma_f32_16x16x32_f16(a1, bk[ksp],     lacc[1][0], 0, 0, 0);
            lacc[1][1] = __builtin_amdgcn_mfma_f32_16x16x32_f16(a1, bk[4 + ksp], lacc[1][1], 0, 0, 0);
        }
        if (ns == 1) {
#pragma unroll
            for (int i = 0; i < 2; i++)
#pragma unroll
                for (int j = 0; j < 2; j++)
                    *(float4v*)&scr_h[(j * 16 + l15) * 36 + i * 16 + lq * 4] = lacc[i][j];
        }
        __syncthreads();        // (2) scratch ready; Qs reads complete
        if (ns == 0) {
            float* dst = lp_g + (size_t)nh * 1024;
#pragma unroll
            for (int i = 0; i < 2; i++)
#pragma unroll
                for (int j = 0; j < 2; j++) {
                    float4v o = lacc[i][j];
                    float4v p4 = *(const float4v*)&scr_h[(j * 16 + l15) * 36 + i * 16 + lq * 4];
                    o += p4;
                    int rb = i * 16 + lq * 4;
#pragma unroll
                    for (int rr = 0; rr < 4; rr++)
                        dst[(rb + rr) * 32 + j * 16 + l15] = o[rr];
                }
        }
    }
}

// ---------------------------------------------------------------------------
// K3: reduce 256 chunk-partials + softmax  [unchanged]
// ---------------------------------------------------------------------------
__global__ __launch_bounds__(256)
void softmax_kernel(const float* __restrict__ Lpart, float* __restrict__ Lsm)
{
    __shared__ float red[32][8][32];
    const int t = threadIdx.x;
    const int rl = t & 7, cs = t >> 3;
    const int row = blockIdx.x * 8 + rl;
    const int b = row >> 8, nh = (row >> 5) & 7, qd = row & 31;
    float4v p[8];
#pragma unroll
    for (int j4 = 0; j4 < 8; j4++) p[j4] = (float4v){0.f, 0.f, 0.f, 0.f};
    for (int cc = 0; cc < 8; cc++) {
        int chunk = cs + cc * 32;
        const float* src = Lpart + (((size_t)chunk * 2 + b) * 8 + nh) * 1024 + qd * 32;
#pragma unroll
        for (int j4 = 0; j4 < 8; j4++) p[j4] += *(const float4v*)(src + j4 * 4);
    }
#pragma unroll
    for (int j4 = 0; j4 < 8; j4++) *(float4v*)&red[cs][rl][j4 * 4] = p[j4];
    __syncthreads();
    const int r2 = t >> 5, j = t & 31;
    float s = 0.f;
#pragma unroll
    for (int c2 = 0; c2 < 32; c2++) s += red[c2][r2][j];
    float mx = s;
#pragma unroll
    for (int off = 16; off >= 1; off >>= 1) mx = fmaxf(mx, __shfl_xor(mx, off, 32));
    float e = expf((s - mx) * 0.125f);
    float sum = e;
#pragma unroll
    for (int off = 16; off >= 1; off >>= 1) sum += __shfl_xor(sum, off, 32);
    Lsm[(size_t)(blockIdx.x * 8 + r2) * 32 + j] = e / sum;
}

// ---------------------------------------------------------------------------
// K4: attn @ V  [unchanged]
// ---------------------------------------------------------------------------
__global__ __launch_bounds__(256)
void attn_v_kernel(const _Float16* __restrict__ kv_t,
                   const float* __restrict__ attn,
                   _Float16* __restrict__ o_t)
{
    __shared__ float as_[2048];
    const int wq = blockIdx.x, hl = blockIdx.y;
    const int b = blockIdx.z >> 2, rc = blockIdx.z & 3;
    const int t = threadIdx.x;
    {
        const float* src = attn + (size_t)b * 8192 + rc * 2048;
#pragma unroll
        for (int ll = 0; ll < 2; ll++) {
            int idx = (t + ll * 256) * 4;
            *(float4v*)(&as_[idx]) = *(const float4v*)(src + idx);
        }
    }
    __syncthreads();
    const int q4 = t & 127;
    const int half = t >> 7;
    const int tt = q4 >> 4;
    const int vd = (q4 * 4) & 63;
    const int hw = hl * 256 + wq * 8 + tt;
    float4v vreg[32];
#pragma unroll
    for (int j = 0; j < 32; j++) {
        half4v hv = *(const half4v*)(kv_t + ((size_t)((b * 32 + j) * 1024 + hw)) * 128 + 64 + vd);
        vreg[j] = (float4v){(float)hv.x, (float)hv.y, (float)hv.z, (float)hv.w};
    }
    _Float16* outb = o_t + (size_t)b * SS * 512;
#pragma unroll 2
    for (int rr = 0; rr < 32; rr++) {
        int row_l = half * 32 + rr;
        int row = rc * 64 + row_l;
        int hh = row >> 5, d = row & 31;
        const float* arow = &as_[row_l * 32];
        float ax = 0.f, ay = 0.f, az = 0.f, aw = 0.f;
#pragma unroll
        for (int j4 = 0; j4 < 8; j4++) {
            float4v a4 = *(const float4v*)(&arow[j4 * 4]);
            float4v v0 = vreg[j4 * 4 + 0];
            float4v v1 = vreg[j4 * 4 + 1];
            float4v v2 = vreg[j4 * 4 + 2];
            float4v v3 = vreg[j4 * 4 + 3];
            ax = fmaf(a4.x, v0.x, ax); ay = fmaf(a4.x, v0.y, ay);
            az = fmaf(a4.x, v0.z, az); aw = fmaf(a4.x, v0.w, aw);
            ax = fmaf(a4.y, v1.x, ax); ay = fmaf(a4.y, v1.y, ay);
            az = fmaf(a4.y, v1.z, az); aw = fmaf(a4.y, v1.w, aw);
            ax = fmaf(a4.z, v2.x, ax); ay = fmaf(a4.z, v2.y, ay);
            az = fmaf(a4.z, v2.z, az); aw = fmaf(a4.z, v2.w, aw);
            ax = fmaf(a4.w, v3.x, ax); ay = fmaf(a4.w, v3.y, ay);
            az = fmaf(a4.w, v3.z, az); aw = fmaf(a4.w, v3.w, aw);
        }
        int hp = hh * 4 + hl;
        size_t sp = (size_t)d * 1024 + hp * 32 + wq;
        half4v o4;
        o4.x = (_Float16)ax; o4.y = (_Float16)ay; o4.z = (_Float16)az; o4.w = (_Float16)aw;
        *(half4v*)(outb + sp * 512 + q4 * 4) = o4;
    }
}

// ---------------------------------------------------------------------------
// K5: proj GEMM via MFMA + bias + layer_scale  [unchanged]
// ---------------------------------------------------------------------------
__global__ __launch_bounds__(256)
void proj_mfma_kernel(const _Float16* __restrict__ o_t,
                      const _Float16* __restrict__ wp,
                      const float* __restrict__ pb,
                      const float* __restrict__ ls,
                      float* __restrict__ out)
{
    __shared__ _Float16 Ws[128 * 64];
    __shared__ _Float16 Xs[128 * 64];
    const int b = blockIdx.y;
    const int bx = blockIdx.x;
    const int grp = bx >> 4, rem = bx & 15;
    const int s_tile = grp * 8 + (rem & 7);
    const int o_tile = rem >> 3;
    const int s0 = s_tile * 128, o0 = o_tile * 128;
    const int t = threadIdx.x;
    const int w = t >> 6, l = t & 63;
    const int om = (w & 1) * 64, sn = (w >> 1) * 64;

    const int lr = l >> 3;
    const int gch = ((l & 7) - lr) & 7;
    const int m15 = l & 15;
    const int sl0 = ((((l >> 4) + (l & 7)) & 7)) * 8;
    const int sl1 = ((((l >> 4) + 4 + (l & 7)) & 7)) * 8;

    float4v acc[4][4];
#pragma unroll
    for (int i = 0; i < 4; i++)
#pragma unroll
        for (int j = 0; j < 4; j++) acc[i][j] = (float4v){0.f, 0.f, 0.f, 0.f};

    const _Float16* wg = wp + (size_t)(o0 + 32 * w + lr) * 512 + gch * 8;
    const _Float16* xg = o_t + ((size_t)b * SS + s0 + 32 * w + lr) * 512 + gch * 8;
    _Float16* wl = &Ws[(32 * w) * 64];
    _Float16* xl = &Xs[(32 * w) * 64];

    for (int c0 = 0; c0 < 512; c0 += 64) {
#pragma unroll
        for (int rb = 0; rb < 4; rb++) {
            gload16(wg + (size_t)rb * 8 * 512 + c0, wl + rb * 8 * 64);
            gload16(xg + (size_t)rb * 8 * 512 + c0, xl + rb * 8 * 64);
        }
        __syncthreads();
#pragma unroll
        for (int ks = 0; ks < 2; ks++) {
            const int sl = ks ? sl1 : sl0;
            half8v a[4], bb[4];
#pragma unroll
            for (int i = 0; i < 4; i++)
                a[i] = *(const half8v*)&Ws[(om + i * 16 + m15) * 64 + sl];
#pragma unroll
            for (int j = 0; j < 4; j++)
                bb[j] = *(const half8v*)&Xs[(sn + j * 16 + m15) * 64 + sl];
#pragma unroll
            for (int i = 0; i < 4; i++)
#pragma unroll
                for (int j = 0; j < 4; j++)
                    acc[i][j] = __builtin_amdgcn_mfma_f32_16x16x32_f16(a[i], bb[j], acc[i][j], 0, 0, 0);
        }
        __syncthreads();
    }
    const int qd = l >> 4, m = l & 15;
#pragma unroll
    for (int i = 0; i < 4; i++) {
        float pbv[4], lsv[4];
#pragma unroll
        for (int r = 0; r < 4; r++) {
            int o = o0 + om + i * 16 + qd * 4 + r;
            pbv[r] = pb[o];
            lsv[r] = ls[o];
        }
#pragma unroll
        for (int j = 0; j < 4; j++) {
            int s = s0 + sn + j * 16 + m;
#pragma unroll
            for (int r = 0; r < 4; r++) {
                int o = o0 + om + i * 16 + qd * 4 + r;
                out[((size_t)b * 256 + o) * SS + s] = (acc[i][j][r] + pbv[r]) * lsv[r];
            }
        }
    }
}

extern "C" void kernel_launch(void* const* d_in, const int* in_sizes, int n_in,
                              void* d_out, int out_size, void* d_ws, size_t ws_size,
                              hipStream_t stream)
{
    const float* x      = (const float*)d_in[0];
    const float* q_w    = (const float*)d_in[1];
    const float* q_b    = (const float*)d_in[2];
    const float* kv_w   = (const float*)d_in[3];
    const float* kv_b   = (const float*)d_in[4];
    const float* proj_w = (const float*)d_in[5];
    const float* proj_b = (const float*)d_in[6];
    const float* ls     = (const float*)d_in[7];
    float* out = (float*)d_out;

    char* ws = (char*)d_ws;
    _Float16* x_t  = (_Float16*)(ws);                        // 33,554,432 B
    _Float16* o_t  = (_Float16*)(ws + 33554432);             // 67,108,864 B
    float*    Lpart= (float*)   (ws + 33554432);             // 16,777,216 B, aliases o_t
    _Float16* kv_t = (_Float16*)(ws + 100663296);            // 16,777,216 B
    float*    Lsm  = (float*)   (ws + 117440512);            //     65,536 B
    _Float16* wq_f = (_Float16*)(ws + 117506048);            //    262,144 B (fragment layout)
    _Float16* wkv  = (_Float16*)(ws + 117768192);            //     65,536 B
    _Float16* wp   = (_Float16*)(ws + 117833728);            //    262,144 B

    static bool fql_attr_set = false;
    if (!fql_attr_set) {
        hipFuncSetAttribute(reinterpret_cast<const void*>(fq_logits_kernel),
                            hipFuncAttributeMaxDynamicSharedMemorySize, FQL_LDS_BYTES);
        fql_attr_set = true;
    }

    cvt_x_kernel<<<dim3(512, 4, 2), 256, 0, stream>>>(x, x_t);
    cvt_w3_kernel<<<dim3(288), 256, 0, stream>>>(q_w, wq_f, kv_w, wkv, proj_w, wp);

    convkv_kernel<<<dim3(256, 2), 256, 0, stream>>>(x_t, wkv, kv_b, kv_t);
    fq_logits_kernel<<<dim3(256, 2), 512, FQL_LDS_BYTES, stream>>>(x_t, wq_f, q_b, kv_t, Lpart);
    softmax_kernel<<<dim3(64), 256, 0, stream>>>(Lpart, Lsm);
    attn_v_kernel<<<dim3(32, 4, 8), 256, 0, stream>>>(kv_t, Lsm, o_t);
    proj_mfma_kernel<<<dim3(512, 2), 256, 0, stream>>>(o_t, wp, proj_b, ls, out);
}